// Round 7
// baseline (300.628 us; speedup 1.0000x reference)
//
#include <hip/hip_runtime.h>
#include <hip/hip_bf16.h>
#include <stdint.h>

#define N_ROWS 32768
#define K_CENT 1024
#define D_DIM  512

typedef __attribute__((ext_vector_type(8))) short bf16x8;    // MFMA A/B frag (8 bf16)
typedef __attribute__((ext_vector_type(4))) float f32x4;     // MFMA C/D frag
typedef __attribute__((ext_vector_type(8))) unsigned short u16x8;

// Persistent scratch as device globals (avoids dependence on ws_size).
__device__ unsigned short g_cb[K_CENT * D_DIM];  // centers in bf16, [K][D]
__device__ float          g_c2[K_CENT];          // ||c_k||^2 (fp32)

static __device__ __forceinline__ unsigned short f2bf(float x) {
    // round-to-nearest-even fp32 -> bf16 (inputs are finite)
    unsigned u = __float_as_uint(x);
    return (unsigned short)((u + 0x7FFFu + ((u >> 16) & 1u)) >> 16);
}

__global__ __launch_bounds__(128) void prep_centers(const float* __restrict__ centers) {
    const int row = blockIdx.x;          // 1024 rows
    const int t   = threadIdx.x;         // 128 threads, 4 floats each
    const float4 v = *reinterpret_cast<const float4*>(centers + (size_t)row * D_DIM + t * 4);
    float sq = v.x * v.x + v.y * v.y + v.z * v.z + v.w * v.w;
    ushort4 b;
    b.x = f2bf(v.x); b.y = f2bf(v.y); b.z = f2bf(v.z); b.w = f2bf(v.w);
    *reinterpret_cast<ushort4*>(g_cb + (size_t)row * D_DIM + t * 4) = b;
    #pragma unroll
    for (int m = 1; m < 64; m <<= 1) sq += __shfl_xor(sq, m);
    __shared__ float p2[2];
    if ((t & 63) == 0) p2[t >> 6] = sq;
    __syncthreads();
    if (t == 0) g_c2[row] = p2[0] + p2[1];
}

// Stage one half-tile of B (512 center-rows x 32 d-elems, bf16 = 32KB) via
// global_load_lds width=16. LDS layout [ds=4][r=512][8] so fragment reads are
// 16B-stride across lanes (bank-conflict-free). 32 chunks of 1KB; wave w does 4.
static __device__ __forceinline__ void stageB(unsigned short* bbuf, int w, int l,
                                              int k, int half) {
    #pragma unroll
    for (int j = 0; j < 4; ++j) {
        const int p  = w * 4 + j;
        const int ds = p >> 3;          // 0..3  (d sub-slot of 8 elems)
        const int rc = p & 7;           // 0..7  (64-row chunk)
        unsigned short* ldst = bbuf + ((size_t)(ds * 512 + rc * 64)) * 8;
        const unsigned short* gsrc =
            g_cb + ((size_t)(half * 512 + rc * 64 + l) * D_DIM + k * 32 + ds * 8);
        __builtin_amdgcn_global_load_lds(
            (const __attribute__((address_space(1))) void*)gsrc,
            (__attribute__((address_space(3))) void*)ldst, 16, 0, 0);
    }
}

static __device__ __forceinline__ void compute_half(const unsigned short* A_lds,
                                                    const unsigned short* bbuf,
                                                    int k, int w, int l15, int l4,
                                                    f32x4 (&acc)[4][4]) {
    bf16x8 a[4], b[4];
    #pragma unroll
    for (int mi = 0; mi < 4; ++mi)
        a[mi] = *reinterpret_cast<const bf16x8*>(
            &A_lds[((size_t)((k * 4 + l4) * 64 + mi * 16 + l15)) * 8]);
    #pragma unroll
    for (int ni = 0; ni < 4; ++ni)
        b[ni] = *reinterpret_cast<const bf16x8*>(
            &bbuf[((size_t)(l4 * 512 + w * 64 + ni * 16 + l15)) * 8]);
    #pragma unroll
    for (int mi = 0; mi < 4; ++mi)
        #pragma unroll
        for (int ni = 0; ni < 4; ++ni)
            acc[mi][ni] = __builtin_amdgcn_mfma_f32_16x16x32_bf16(a[mi], b[ni],
                                                                  acc[mi][ni], 0, 0, 0);
}

__global__ __launch_bounds__(512, 2) void fuzzy_mu_kernel(const float* __restrict__ feats,
                                                          float* __restrict__ out) {
    // LDS: A 64KB + B 2x32KB + 0.5KB = 128.5KB -> 1 block/CU, 2 waves/SIMD
    __shared__ unsigned short A_lds[64 * 64 * 8];      // [ds=64][row=64][e=8]
    __shared__ unsigned short B_lds[2][4 * 512 * 8];   // double-buffered half-tiles
    __shared__ float x2s[64];
    __shared__ float rs[64];

    const int tid = threadIdx.x;
    const int l   = tid & 63;
    const int w   = tid >> 6;
    const int l15 = l & 15;
    const int l4  = l >> 4;

    // XCD-aware swizzle (512 blocks % 8 == 0 -> bijective)
    const int bid  = blockIdx.x;
    const int bswz = (bid & 7) * 64 + (bid >> 3);
    const int nb   = bswz * 64;

    if (tid < 64) { rs[tid] = 0.0f; }

    // ---- Stage A: fp32 -> bf16 into LDS (resident all K-steps) + x2 ----
    {
        const int row = tid >> 3;   // 0..63
        const int s   = tid & 7;
        const float* src = feats + (size_t)(nb + row) * D_DIM;
        float sq = 0.f;
        #pragma unroll
        for (int j = 0; j < 8; ++j) {
            const int c0 = s * 64 + j * 8;
            const float4 v0 = *reinterpret_cast<const float4*>(src + c0);
            const float4 v1 = *reinterpret_cast<const float4*>(src + c0 + 4);
            sq += v0.x * v0.x + v0.y * v0.y + v0.z * v0.z + v0.w * v0.w;
            sq += v1.x * v1.x + v1.y * v1.y + v1.z * v1.z + v1.w * v1.w;
            u16x8 pk;
            pk[0] = f2bf(v0.x); pk[1] = f2bf(v0.y); pk[2] = f2bf(v0.z); pk[3] = f2bf(v0.w);
            pk[4] = f2bf(v1.x); pk[5] = f2bf(v1.y); pk[6] = f2bf(v1.z); pk[7] = f2bf(v1.w);
            const int ds = s * 8 + j;
            *reinterpret_cast<u16x8*>(&A_lds[((size_t)(ds * 64 + row)) * 8]) = pk;
        }
        sq += __shfl_xor(sq, 1);
        sq += __shfl_xor(sq, 2);
        sq += __shfl_xor(sq, 4);
        if (s == 0) x2s[row] = sq;
    }

    f32x4 acc0[4][4], acc1[4][4];
    const f32x4 zz = {0.f, 0.f, 0.f, 0.f};
    #pragma unroll
    for (int mi = 0; mi < 4; ++mi)
        #pragma unroll
        for (int ni = 0; ni < 4; ++ni) { acc0[mi][ni] = zz; acc1[mi][ni] = zz; }

    // Prologue: buf0 <- (k=0, half=0); full drain publishes A_lds + buf0.
    stageB(B_lds[0], w, l, 0, 0);
    __syncthreads();

    // ---- K-loop: verified minimal 2-phase template (T3 recipe) ----
    // Each phase: STAGE(other buf, next half-tile) -> compute(current buf)
    // -> __syncthreads() (full vmcnt/lgkm drain + barrier publishes the
    // staged buffer and retires all reads of the current one).
    for (int k = 0; k < 16; ++k) {
        stageB(B_lds[1], w, l, k, 1);                     // prefetch (k, half1)
        compute_half(A_lds, B_lds[0], k, w, l15, l4, acc0);
        __syncthreads();                                  // buf1 ready; buf0 reads done

        if (k < 15) stageB(B_lds[0], w, l, k + 1, 0);     // prefetch (k+1, half0)
        compute_half(A_lds, B_lds[1], k, w, l15, l4, acc1);
        __syncthreads();                                  // buf0 ready; buf1 reads done
    }

    // ---- Epilogue: d = x2 - 2*dot + c2 ; inv = 1/d ; block-local row sums ----
    float rowpart[4][4];
    #pragma unroll
    for (int mi = 0; mi < 4; ++mi)
        #pragma unroll
        for (int j = 0; j < 4; ++j) rowpart[mi][j] = 0.f;

    #pragma unroll
    for (int mi = 0; mi < 4; ++mi) {
        #pragma unroll
        for (int ni = 0; ni < 4; ++ni) {
            const int cb  = w * 64 + ni * 16 + l15;
            const float c2v0 = g_c2[cb];
            const float c2v1 = g_c2[512 + cb];
            #pragma unroll
            for (int j = 0; j < 4; ++j) {
                const float xv = x2s[mi * 16 + l4 * 4 + j];
                const float d0 = xv - 2.f * acc0[mi][ni][j] + c2v0;
                const float d1 = xv - 2.f * acc1[mi][ni][j] + c2v1;
                const float i0 = 1.f / d0;
                const float i1 = 1.f / d1;
                acc0[mi][ni][j] = i0;
                acc1[mi][ni][j] = i1;
                rowpart[mi][j] += i0 + i1;
            }
        }
    }
    #pragma unroll
    for (int mi = 0; mi < 4; ++mi) {
        #pragma unroll
        for (int j = 0; j < 4; ++j) {
            float v = rowpart[mi][j];
            v += __shfl_xor(v, 1);
            v += __shfl_xor(v, 2);
            v += __shfl_xor(v, 4);
            v += __shfl_xor(v, 8);   // sum over the 16 cols held by this l4-group
            if (l15 == 0) atomicAdd(&rs[mi * 16 + l4 * 4 + j], v);
        }
    }
    __syncthreads();

    #pragma unroll
    for (int mi = 0; mi < 4; ++mi) {
        #pragma unroll
        for (int j = 0; j < 4; ++j) {
            const int rl = mi * 16 + l4 * 4 + j;
            const float rinv = 1.0f / rs[rl];
            float* op = out + (size_t)(nb + rl) * K_CENT + w * 64 + l15;
            #pragma unroll
            for (int ni = 0; ni < 4; ++ni) {
                op[ni * 16]       = acc0[mi][ni][j] * rinv;
                op[512 + ni * 16] = acc1[mi][ni][j] * rinv;
            }
        }
    }
}

extern "C" void kernel_launch(void* const* d_in, const int* in_sizes, int n_in,
                              void* d_out, int out_size, void* d_ws, size_t ws_size,
                              hipStream_t stream) {
    const float* feats = (const float*)d_in[0];   // [32768, 512] fp32
    const float* cents = (const float*)d_in[1];   // [1024, 512] fp32
    float* out = (float*)d_out;                   // [32768, 1024] fp32

    prep_centers<<<K_CENT, 128, 0, stream>>>(cents);
    fuzzy_mu_kernel<<<N_ROWS / 64, 512, 0, stream>>>(feats, out);
}

// Round 8
// 249.272 us; speedup vs baseline: 1.2060x; 1.2060x over previous
//
#include <hip/hip_runtime.h>
#include <hip/hip_bf16.h>
#include <stdint.h>

#define N_ROWS 32768
#define K_CENT 1024
#define D_DIM  512

typedef __attribute__((ext_vector_type(8))) short bf16x8;    // MFMA A/B frag (8 bf16)
typedef __attribute__((ext_vector_type(4))) float f32x4;     // MFMA C/D frag
typedef __attribute__((ext_vector_type(8))) unsigned short u16x8;

// Centers in bf16, PRE-TRANSPOSED into staging order so the K-loop's
// global_load_lds reads are contiguous 1KB per wave:
//   elem(h,k,p,l,e) at (((h*16+k)*32 + p)*64 + l)*8 + e
// where center row r = h*512 + (p&7)*64 + l, dim d = k*32 + (p>>3)*8 + e.
__device__ unsigned short g_cbT[K_CENT * D_DIM];
__device__ float          g_c2[K_CENT];          // ||c_k||^2 (fp32)

static __device__ __forceinline__ unsigned short f2bf(float x) {
    // round-to-nearest-even fp32 -> bf16 (inputs are finite)
    unsigned u = __float_as_uint(x);
    return (unsigned short)((u + 0x7FFFu + ((u >> 16) & 1u)) >> 16);
}

// One wave per center row: read 2KB row coalesced, emit 16B to the
// transposed layout, wave-reduce ||c||^2.
__global__ __launch_bounds__(64) void prep_centers(const float* __restrict__ centers) {
    const int row = blockIdx.x;          // 0..1023
    const int s   = threadIdx.x;         // 0..63, handles d = s*8..s*8+7
    const float4 v0 = *reinterpret_cast<const float4*>(centers + (size_t)row * D_DIM + s * 8);
    const float4 v1 = *reinterpret_cast<const float4*>(centers + (size_t)row * D_DIM + s * 8 + 4);
    float sq = v0.x * v0.x + v0.y * v0.y + v0.z * v0.z + v0.w * v0.w
             + v1.x * v1.x + v1.y * v1.y + v1.z * v1.z + v1.w * v1.w;
    u16x8 pk;
    pk[0] = f2bf(v0.x); pk[1] = f2bf(v0.y); pk[2] = f2bf(v0.z); pk[3] = f2bf(v0.w);
    pk[4] = f2bf(v1.x); pk[5] = f2bf(v1.y); pk[6] = f2bf(v1.z); pk[7] = f2bf(v1.w);
    const int h  = row >> 9;             // half
    const int rc = (row >> 6) & 7;       // 64-row chunk
    const int l  = row & 63;             // lane slot
    const int k  = s >> 2;               // K-step
    const int ds = s & 3;                // d sub-slot
    const size_t off = ((size_t)(((h * 16 + k) * 32) + ds * 8 + rc) * 64 + l) * 8;
    *reinterpret_cast<u16x8*>(g_cbT + off) = pk;
    #pragma unroll
    for (int m = 1; m < 64; m <<= 1) sq += __shfl_xor(sq, m);
    if (s == 0) g_c2[row] = sq;
}

// Stage one half-tile of B (512 center-rows x 32 d-elems, bf16 = 32KB) via
// global_load_lds width=16. Source is contiguous 1KB per wave-instruction
// (g_cbT staging order); LDS dest linear (wave-uniform base + lane*16).
static __device__ __forceinline__ void stageB(unsigned short* bbuf, int w, int l,
                                              int k, int half) {
    #pragma unroll
    for (int j = 0; j < 4; ++j) {
        const int p = w * 4 + j;        // chunk 0..31
        unsigned short* ldst = bbuf + (size_t)p * 512;
        const unsigned short* gsrc =
            g_cbT + ((size_t)(((half * 16 + k) * 32) + p)) * 512 + l * 8;
        __builtin_amdgcn_global_load_lds(
            (const __attribute__((address_space(1))) void*)gsrc,
            (__attribute__((address_space(3))) void*)ldst, 16, 0, 0);
    }
}

static __device__ __forceinline__ void compute_half(const unsigned short* A_lds,
                                                    const unsigned short* bbuf,
                                                    int k, int w, int l15, int l4,
                                                    f32x4 (&acc)[4][4]) {
    bf16x8 a[4], b[4];
    #pragma unroll
    for (int mi = 0; mi < 4; ++mi)
        a[mi] = *reinterpret_cast<const bf16x8*>(
            &A_lds[((size_t)((k * 4 + l4) * 64 + mi * 16 + l15)) * 8]);
    #pragma unroll
    for (int ni = 0; ni < 4; ++ni)
        b[ni] = *reinterpret_cast<const bf16x8*>(
            &bbuf[((size_t)(l4 * 512 + w * 64 + ni * 16 + l15)) * 8]);
    #pragma unroll
    for (int mi = 0; mi < 4; ++mi)
        #pragma unroll
        for (int ni = 0; ni < 4; ++ni)
            acc[mi][ni] = __builtin_amdgcn_mfma_f32_16x16x32_bf16(a[mi], b[ni],
                                                                  acc[mi][ni], 0, 0, 0);
}

__global__ __launch_bounds__(512, 2) void fuzzy_mu_kernel(const float* __restrict__ feats,
                                                          float* __restrict__ out) {
    // LDS: A 64KB + B 2x32KB + 0.5KB = 128.5KB -> 1 block/CU, 2 waves/SIMD
    __shared__ unsigned short A_lds[64 * 64 * 8];      // [ds=64][row=64][e=8]
    __shared__ unsigned short B_lds[2][4 * 512 * 8];   // double-buffered half-tiles
    __shared__ float x2s[64];
    __shared__ float rs[64];

    const int tid = threadIdx.x;
    const int l   = tid & 63;
    const int w   = tid >> 6;
    const int l15 = l & 15;
    const int l4  = l >> 4;

    // XCD-aware swizzle (512 blocks % 8 == 0 -> bijective)
    const int bid  = blockIdx.x;
    const int bswz = (bid & 7) * 64 + (bid >> 3);
    const int nb   = bswz * 64;

    if (tid < 64) { rs[tid] = 0.0f; }

    // ---- Stage A: fp32 -> bf16 into LDS (resident all K-steps) + x2 ----
    {
        const int row = tid >> 3;   // 0..63
        const int s   = tid & 7;
        const float* src = feats + (size_t)(nb + row) * D_DIM;
        float sq = 0.f;
        #pragma unroll
        for (int j = 0; j < 8; ++j) {
            const int c0 = s * 64 + j * 8;
            const float4 v0 = *reinterpret_cast<const float4*>(src + c0);
            const float4 v1 = *reinterpret_cast<const float4*>(src + c0 + 4);
            sq += v0.x * v0.x + v0.y * v0.y + v0.z * v0.z + v0.w * v0.w;
            sq += v1.x * v1.x + v1.y * v1.y + v1.z * v1.z + v1.w * v1.w;
            u16x8 pk;
            pk[0] = f2bf(v0.x); pk[1] = f2bf(v0.y); pk[2] = f2bf(v0.z); pk[3] = f2bf(v0.w);
            pk[4] = f2bf(v1.x); pk[5] = f2bf(v1.y); pk[6] = f2bf(v1.z); pk[7] = f2bf(v1.w);
            const int ds = s * 8 + j;
            *reinterpret_cast<u16x8*>(&A_lds[((size_t)(ds * 64 + row)) * 8]) = pk;
        }
        sq += __shfl_xor(sq, 1);
        sq += __shfl_xor(sq, 2);
        sq += __shfl_xor(sq, 4);
        if (s == 0) x2s[row] = sq;
    }

    f32x4 acc0[4][4], acc1[4][4];
    const f32x4 zz = {0.f, 0.f, 0.f, 0.f};
    #pragma unroll
    for (int mi = 0; mi < 4; ++mi)
        #pragma unroll
        for (int ni = 0; ni < 4; ++ni) { acc0[mi][ni] = zz; acc1[mi][ni] = zz; }

    // Prologue: buf0 <- (k=0, half=0); full drain publishes A_lds + buf0.
    stageB(B_lds[0], w, l, 0, 0);
    __syncthreads();

    // ---- K-loop: verified minimal 2-phase template (T3 recipe) ----
    for (int k = 0; k < 16; ++k) {
        stageB(B_lds[1], w, l, k, 1);                     // prefetch (k, half1)
        compute_half(A_lds, B_lds[0], k, w, l15, l4, acc0);
        __syncthreads();                                  // buf1 ready; buf0 reads done

        if (k < 15) stageB(B_lds[0], w, l, k + 1, 0);     // prefetch (k+1, half0)
        compute_half(A_lds, B_lds[1], k, w, l15, l4, acc1);
        __syncthreads();                                  // buf0 ready; buf1 reads done
    }

    // ---- Epilogue: d = x2 - 2*dot + c2 ; inv = 1/d ; block-local row sums ----
    float rowpart[4][4];
    #pragma unroll
    for (int mi = 0; mi < 4; ++mi)
        #pragma unroll
        for (int j = 0; j < 4; ++j) rowpart[mi][j] = 0.f;

    #pragma unroll
    for (int mi = 0; mi < 4; ++mi) {
        #pragma unroll
        for (int ni = 0; ni < 4; ++ni) {
            const int cb  = w * 64 + ni * 16 + l15;
            const float c2v0 = g_c2[cb];
            const float c2v1 = g_c2[512 + cb];
            #pragma unroll
            for (int j = 0; j < 4; ++j) {
                const float xv = x2s[mi * 16 + l4 * 4 + j];
                const float d0 = xv - 2.f * acc0[mi][ni][j] + c2v0;
                const float d1 = xv - 2.f * acc1[mi][ni][j] + c2v1;
                const float i0 = 1.f / d0;
                const float i1 = 1.f / d1;
                acc0[mi][ni][j] = i0;
                acc1[mi][ni][j] = i1;
                rowpart[mi][j] += i0 + i1;
            }
        }
    }
    #pragma unroll
    for (int mi = 0; mi < 4; ++mi) {
        #pragma unroll
        for (int j = 0; j < 4; ++j) {
            float v = rowpart[mi][j];
            v += __shfl_xor(v, 1);
            v += __shfl_xor(v, 2);
            v += __shfl_xor(v, 4);
            v += __shfl_xor(v, 8);   // sum over the 16 cols held by this l4-group
            if (l15 == 0) atomicAdd(&rs[mi * 16 + l4 * 4 + j], v);
        }
    }
    __syncthreads();

    #pragma unroll
    for (int mi = 0; mi < 4; ++mi) {
        #pragma unroll
        for (int j = 0; j < 4; ++j) {
            const int rl = mi * 16 + l4 * 4 + j;
            const float rinv = 1.0f / rs[rl];
            float* op = out + (size_t)(nb + rl) * K_CENT + w * 64 + l15;
            #pragma unroll
            for (int ni = 0; ni < 4; ++ni) {
                op[ni * 16]       = acc0[mi][ni][j] * rinv;
                op[512 + ni * 16] = acc1[mi][ni][j] * rinv;
            }
        }
    }
}

extern "C" void kernel_launch(void* const* d_in, const int* in_sizes, int n_in,
                              void* d_out, int out_size, void* d_ws, size_t ws_size,
                              hipStream_t stream) {
    const float* feats = (const float*)d_in[0];   // [32768, 512] fp32
    const float* cents = (const float*)d_in[1];   // [1024, 512] fp32
    float* out = (float*)d_out;                   // [32768, 1024] fp32

    prep_centers<<<K_CENT, 64, 0, stream>>>(cents);
    fuzzy_mu_kernel<<<N_ROWS / 64, 512, 0, stream>>>(feats, out);
}

// Round 12
// 221.862 us; speedup vs baseline: 1.3550x; 1.1235x over previous
//
#include <hip/hip_runtime.h>
#include <hip/hip_bf16.h>
#include <stdint.h>

#define N_ROWS 32768
#define K_CENT 1024
#define D_DIM  512

typedef __attribute__((ext_vector_type(8))) short bf16x8;    // MFMA A/B frag (8 bf16)
typedef __attribute__((ext_vector_type(4))) float f32x4;     // MFMA C/D frag
typedef __attribute__((ext_vector_type(8))) unsigned short u16x8;

// Centers in bf16, pre-swizzled into MFMA FRAGMENT order so the main kernel
// loads B directly from global (L2-resident, 1MB) into VGPRs:
//   elem(k, w, ni, l, e) at (((k*16 + w)*4 + ni)*64 + l)*8 + e
// where center row r = w*64 + ni*16 + (l&15), dim d = k*32 + (l>>4)*8 + e.
__device__ unsigned short g_cbF[K_CENT * D_DIM];
__device__ float          g_c2[K_CENT];          // ||c_k||^2 (fp32)

static __device__ __forceinline__ unsigned short f2bf(float x) {
    // round-to-nearest-even fp32 -> bf16 (inputs are finite)
    unsigned u = __float_as_uint(x);
    return (unsigned short)((u + 0x7FFFu + ((u >> 16) & 1u)) >> 16);
}

// One wave per center row: coalesced 2KB row read, fragment-order 16B store,
// wave-reduce ||c||^2.
__global__ __launch_bounds__(64) void prep_centers(const float* __restrict__ centers) {
    const int row = blockIdx.x;          // 0..1023
    const int s   = threadIdx.x;         // 0..63, handles d = s*8..s*8+7
    const float4 v0 = *reinterpret_cast<const float4*>(centers + (size_t)row * D_DIM + s * 8);
    const float4 v1 = *reinterpret_cast<const float4*>(centers + (size_t)row * D_DIM + s * 8 + 4);
    float sq = v0.x * v0.x + v0.y * v0.y + v0.z * v0.z + v0.w * v0.w
             + v1.x * v1.x + v1.y * v1.y + v1.z * v1.z + v1.w * v1.w;
    u16x8 pk;
    pk[0] = f2bf(v0.x); pk[1] = f2bf(v0.y); pk[2] = f2bf(v0.z); pk[3] = f2bf(v0.w);
    pk[4] = f2bf(v1.x); pk[5] = f2bf(v1.y); pk[6] = f2bf(v1.z); pk[7] = f2bf(v1.w);
    const int k   = s >> 2;              // K-step 0..15
    const int l4  = s & 3;               // k-slice within fragment
    const int w   = row >> 6;            // consuming wave 0..15
    const int ni  = (row >> 4) & 3;      // fragment col-block
    const int l15 = row & 15;            // lane low bits
    const int l   = l4 * 16 + l15;       // lane
    const size_t off = ((size_t)(((k * 16 + w) * 4 + ni) * 64 + l)) * 8;
    *reinterpret_cast<u16x8*>(g_cbF + off) = pk;
    #pragma unroll
    for (int m = 1; m < 64; m <<= 1) sq += __shfl_xor(sq, m);
    if (s == 0) g_c2[row] = sq;
}

// 1024 threads = 16 waves. Block output: 64 rows x 1024 cols. Wave w owns
// cols w*64..w*64+63. A (64x512 bf16) resident in LDS; B fragments loaded
// straight from L2. NO barriers in the K-loop.
__global__ __launch_bounds__(1024) void fuzzy_mu_kernel(const float* __restrict__ feats,
                                                        float* __restrict__ out) {
    __shared__ unsigned short A_lds[64 * 64 * 8];      // [dslot=64][row=64][e=8] = 64KB
    __shared__ float x2s[64];
    __shared__ float rs[64];

    const int tid = threadIdx.x;
    const int l   = tid & 63;
    const int w   = tid >> 6;            // 0..15
    const int l15 = l & 15;
    const int l4  = l >> 4;

    // XCD-aware swizzle (512 blocks % 8 == 0 -> bijective)
    const int bid  = blockIdx.x;
    const int bswz = (bid & 7) * 64 + (bid >> 3);
    const int nb   = bswz * 64;

    if (tid < 64) rs[tid] = 0.0f;

    // ---- Stage A: fp32 -> bf16 into LDS + x2 (16 threads per row) ----
    {
        const int row = tid >> 4;        // 0..63  (= w*4 + l4)
        const int s   = tid & 15;        // = l15
        const float* src = feats + (size_t)(nb + row) * D_DIM;
        float sq = 0.f;
        #pragma unroll
        for (int j = 0; j < 4; ++j) {
            const int c0 = s * 32 + j * 8;
            const float4 v0 = *reinterpret_cast<const float4*>(src + c0);
            const float4 v1 = *reinterpret_cast<const float4*>(src + c0 + 4);
            sq += v0.x * v0.x + v0.y * v0.y + v0.z * v0.z + v0.w * v0.w;
            sq += v1.x * v1.x + v1.y * v1.y + v1.z * v1.z + v1.w * v1.w;
            u16x8 pk;
            pk[0] = f2bf(v0.x); pk[1] = f2bf(v0.y); pk[2] = f2bf(v0.z); pk[3] = f2bf(v0.w);
            pk[4] = f2bf(v1.x); pk[5] = f2bf(v1.y); pk[6] = f2bf(v1.z); pk[7] = f2bf(v1.w);
            const int ds = s * 4 + j;    // d-octet 0..63
            *reinterpret_cast<u16x8*>(&A_lds[((size_t)(ds * 64 + row)) * 8]) = pk;
        }
        sq += __shfl_xor(sq, 1);
        sq += __shfl_xor(sq, 2);
        sq += __shfl_xor(sq, 4);
        sq += __shfl_xor(sq, 8);
        if (s == 0) x2s[row] = sq;
    }

    f32x4 acc[4][4];
    const f32x4 zz = {0.f, 0.f, 0.f, 0.f};
    #pragma unroll
    for (int mi = 0; mi < 4; ++mi)
        #pragma unroll
        for (int ni = 0; ni < 4; ++ni) acc[mi][ni] = zz;

    __syncthreads();   // publish A_lds, x2s, rs — the ONLY pre-epilogue barrier

    // ---- K-loop: barrier-free; B straight from L2 in fragment order ----
    #pragma unroll 2
    for (int k = 0; k < 16; ++k) {
        const unsigned short* bb = g_cbF + ((size_t)(k * 16 + w) * 4) * 512 + l * 8;
        bf16x8 b[4];
        #pragma unroll
        for (int ni = 0; ni < 4; ++ni)
            b[ni] = *reinterpret_cast<const bf16x8*>(bb + ni * 512);
        bf16x8 a[4];
        #pragma unroll
        for (int mi = 0; mi < 4; ++mi)
            a[mi] = *reinterpret_cast<const bf16x8*>(
                &A_lds[((size_t)((k * 4 + l4) * 64 + mi * 16 + l15)) * 8]);
        #pragma unroll
        for (int mi = 0; mi < 4; ++mi)
            #pragma unroll
            for (int ni = 0; ni < 4; ++ni)
                acc[mi][ni] = __builtin_amdgcn_mfma_f32_16x16x32_bf16(a[mi], b[ni],
                                                                      acc[mi][ni], 0, 0, 0);
    }

    // ---- Epilogue: d = x2 - 2*dot + c2 ; inv = 1/d ; block-local row sums ----
    float rowpart[4][4];
    #pragma unroll
    for (int mi = 0; mi < 4; ++mi)
        #pragma unroll
        for (int j = 0; j < 4; ++j) rowpart[mi][j] = 0.f;

    #pragma unroll
    for (int mi = 0; mi < 4; ++mi) {
        #pragma unroll
        for (int ni = 0; ni < 4; ++ni) {
            const float c2v = g_c2[w * 64 + ni * 16 + l15];
            #pragma unroll
            for (int j = 0; j < 4; ++j) {
                const float xv = x2s[mi * 16 + l4 * 4 + j];
                const float dd = xv - 2.f * acc[mi][ni][j] + c2v;
                const float iv = 1.f / dd;
                acc[mi][ni][j] = iv;
                rowpart[mi][j] += iv;
            }
        }
    }
    #pragma unroll
    for (int mi = 0; mi < 4; ++mi) {
        #pragma unroll
        for (int j = 0; j < 4; ++j) {
            float v = rowpart[mi][j];
            v += __shfl_xor(v, 1);
            v += __shfl_xor(v, 2);
            v += __shfl_xor(v, 4);
            v += __shfl_xor(v, 8);   // sum over this wave's 16 cols (l15 group)
            if (l15 == 0) atomicAdd(&rs[mi * 16 + l4 * 4 + j], v);
        }
    }
    __syncthreads();

    #pragma unroll
    for (int mi = 0; mi < 4; ++mi) {
        #pragma unroll
        for (int j = 0; j < 4; ++j) {
            const int rl = mi * 16 + l4 * 4 + j;
            const float rinv = 1.0f / rs[rl];
            float* op = out + (size_t)(nb + rl) * K_CENT + w * 64 + l15;
            #pragma unroll
            for (int ni = 0; ni < 4; ++ni)
                op[ni * 16] = acc[mi][ni][j] * rinv;
        }
    }
}

extern "C" void kernel_launch(void* const* d_in, const int* in_sizes, int n_in,
                              void* d_out, int out_size, void* d_ws, size_t ws_size,
                              hipStream_t stream) {
    const float* feats = (const float*)d_in[0];   // [32768, 512] fp32
    const float* cents = (const float*)d_in[1];   // [1024, 512] fp32
    float* out = (float*)d_out;                   // [32768, 1024] fp32

    prep_centers<<<K_CENT, 64, 0, stream>>>(cents);
    fuzzy_mu_kernel<<<N_ROWS / 64, 1024, 0, stream>>>(feats, out);
}

// Round 13
// 214.133 us; speedup vs baseline: 1.4039x; 1.0361x over previous
//
#include <hip/hip_runtime.h>
#include <hip/hip_bf16.h>
#include <stdint.h>

#define N_ROWS 32768
#define K_CENT 1024
#define D_DIM  512

typedef __attribute__((ext_vector_type(8))) short bf16x8;    // MFMA A/B frag (8 bf16)
typedef __attribute__((ext_vector_type(4))) float f32x4;     // MFMA C/D frag
typedef __attribute__((ext_vector_type(8))) unsigned short u16x8;

// Centers in bf16, pre-swizzled into MFMA FRAGMENT order. Fragment slot
// (k, w, ni, l=l4*16+l15, e) holds center row  w*64 + l15*4 + ni  at dim
// k*32 + l4*8 + e. The l15*4+ni (vs ni*16+l15) permutation makes each
// epilogue thread's 4 output columns CONTIGUOUS -> float4 stores.
__device__ unsigned short g_cbF[K_CENT * D_DIM];
__device__ float          g_c2[K_CENT];          // ||c_k||^2 (fp32)

static __device__ __forceinline__ unsigned short f2bf(float x) {
    // round-to-nearest-even fp32 -> bf16 (inputs are finite)
    unsigned u = __float_as_uint(x);
    return (unsigned short)((u + 0x7FFFu + ((u >> 16) & 1u)) >> 16);
}

// One wave per center row: coalesced 2KB row read, fragment-order 16B store,
// wave-reduce ||c||^2.
__global__ __launch_bounds__(64) void prep_centers(const float* __restrict__ centers) {
    const int row = blockIdx.x;          // 0..1023
    const int s   = threadIdx.x;         // 0..63, handles d = s*8..s*8+7
    const float4 v0 = *reinterpret_cast<const float4*>(centers + (size_t)row * D_DIM + s * 8);
    const float4 v1 = *reinterpret_cast<const float4*>(centers + (size_t)row * D_DIM + s * 8 + 4);
    float sq = v0.x * v0.x + v0.y * v0.y + v0.z * v0.z + v0.w * v0.w
             + v1.x * v1.x + v1.y * v1.y + v1.z * v1.z + v1.w * v1.w;
    u16x8 pk;
    pk[0] = f2bf(v0.x); pk[1] = f2bf(v0.y); pk[2] = f2bf(v0.z); pk[3] = f2bf(v0.w);
    pk[4] = f2bf(v1.x); pk[5] = f2bf(v1.y); pk[6] = f2bf(v1.z); pk[7] = f2bf(v1.w);
    const int k   = s >> 2;              // K-step 0..15
    const int l4  = s & 3;               // k-slice within fragment
    const int w   = row >> 6;            // consuming wave 0..15
    const int l15 = (row >> 2) & 15;     // lane low bits  (PERMUTED:
    const int ni  = row & 3;             //  center = w*64 + l15*4 + ni)
    const int l   = l4 * 16 + l15;       // lane
    const size_t off = ((size_t)(((k * 16 + w) * 4 + ni) * 64 + l)) * 8;
    *reinterpret_cast<u16x8*>(g_cbF + off) = pk;
    #pragma unroll
    for (int m = 1; m < 64; m <<= 1) sq += __shfl_xor(sq, m);
    if (s == 0) g_c2[row] = sq;
}

// 1024 threads = 16 waves. Block output: 64 rows x 1024 cols. Wave w owns
// cols w*64..w*64+63. A (64x512 bf16) resident in LDS; B fragments loaded
// straight from L2. NO barriers in the K-loop.
__global__ __launch_bounds__(1024) void fuzzy_mu_kernel(const float* __restrict__ feats,
                                                        float* __restrict__ out) {
    __shared__ unsigned short A_lds[64 * 64 * 8];      // [dslot=64][row=64][e=8] = 64KB
    __shared__ float x2s[64];
    __shared__ float rs[64];

    const int tid = threadIdx.x;
    const int l   = tid & 63;
    const int w   = tid >> 6;            // 0..15
    const int l15 = l & 15;
    const int l4  = l >> 4;

    // XCD-aware swizzle (512 blocks % 8 == 0 -> bijective)
    const int bid  = blockIdx.x;
    const int bswz = (bid & 7) * 64 + (bid >> 3);
    const int nb   = bswz * 64;

    if (tid < 64) rs[tid] = 0.0f;

    // ---- Stage A: fp32 -> bf16 into LDS + x2 (16 threads per row) ----
    {
        const int row = tid >> 4;        // 0..63  (= w*4 + l4)
        const int s   = tid & 15;        // = l15
        const float* src = feats + (size_t)(nb + row) * D_DIM;
        float sq = 0.f;
        #pragma unroll
        for (int j = 0; j < 4; ++j) {
            const int c0 = s * 32 + j * 8;
            const float4 v0 = *reinterpret_cast<const float4*>(src + c0);
            const float4 v1 = *reinterpret_cast<const float4*>(src + c0 + 4);
            sq += v0.x * v0.x + v0.y * v0.y + v0.z * v0.z + v0.w * v0.w;
            sq += v1.x * v1.x + v1.y * v1.y + v1.z * v1.z + v1.w * v1.w;
            u16x8 pk;
            pk[0] = f2bf(v0.x); pk[1] = f2bf(v0.y); pk[2] = f2bf(v0.z); pk[3] = f2bf(v0.w);
            pk[4] = f2bf(v1.x); pk[5] = f2bf(v1.y); pk[6] = f2bf(v1.z); pk[7] = f2bf(v1.w);
            const int ds = s * 4 + j;    // d-octet 0..63
            *reinterpret_cast<u16x8*>(&A_lds[((size_t)(ds * 64 + row)) * 8]) = pk;
        }
        sq += __shfl_xor(sq, 1);
        sq += __shfl_xor(sq, 2);
        sq += __shfl_xor(sq, 4);
        sq += __shfl_xor(sq, 8);
        if (s == 0) x2s[row] = sq;
    }

    f32x4 acc[4][4];
    const f32x4 zz = {0.f, 0.f, 0.f, 0.f};
    #pragma unroll
    for (int mi = 0; mi < 4; ++mi)
        #pragma unroll
        for (int ni = 0; ni < 4; ++ni) acc[mi][ni] = zz;

    __syncthreads();   // publish A_lds, x2s, rs — the ONLY pre-epilogue barrier

    // ---- K-loop: barrier-free; B straight from L2 in fragment order ----
    #pragma unroll 2
    for (int k = 0; k < 16; ++k) {
        const unsigned short* bb = g_cbF + ((size_t)(k * 16 + w) * 4) * 512 + l * 8;
        bf16x8 b[4];
        #pragma unroll
        for (int ni = 0; ni < 4; ++ni)
            b[ni] = *reinterpret_cast<const bf16x8*>(bb + ni * 512);
        bf16x8 a[4];
        #pragma unroll
        for (int mi = 0; mi < 4; ++mi)
            a[mi] = *reinterpret_cast<const bf16x8*>(
                &A_lds[((size_t)((k * 4 + l4) * 64 + mi * 16 + l15)) * 8]);
        #pragma unroll
        for (int mi = 0; mi < 4; ++mi)
            #pragma unroll
            for (int ni = 0; ni < 4; ++ni)
                acc[mi][ni] = __builtin_amdgcn_mfma_f32_16x16x32_bf16(a[mi], b[ni],
                                                                      acc[mi][ni], 0, 0, 0);
    }

    // ---- Epilogue: d = x2 - 2*dot + c2 ; inv = rcp(d) ; row sums ; store ----
    // Thread covers cols w*64 + l15*4 + {0,1,2,3}  (contiguous, float4 I/O).
    const float4 c2q = *reinterpret_cast<const float4*>(g_c2 + w * 64 + l15 * 4);

    float rowpart[4][4];
    #pragma unroll
    for (int mi = 0; mi < 4; ++mi)
        #pragma unroll
        for (int j = 0; j < 4; ++j) rowpart[mi][j] = 0.f;

    #pragma unroll
    for (int mi = 0; mi < 4; ++mi) {
        #pragma unroll
        for (int ni = 0; ni < 4; ++ni) {
            const float c2v = (ni == 0) ? c2q.x : (ni == 1) ? c2q.y
                            : (ni == 2) ? c2q.z : c2q.w;
            #pragma unroll
            for (int j = 0; j < 4; ++j) {
                const float xv = x2s[mi * 16 + l4 * 4 + j];
                const float dd = xv - 2.f * acc[mi][ni][j] + c2v;
                const float iv = __builtin_amdgcn_rcpf(dd);
                acc[mi][ni][j] = iv;
                rowpart[mi][j] += iv;
            }
        }
    }
    #pragma unroll
    for (int mi = 0; mi < 4; ++mi) {
        #pragma unroll
        for (int j = 0; j < 4; ++j) {
            float v = rowpart[mi][j];
            v += __shfl_xor(v, 1);
            v += __shfl_xor(v, 2);
            v += __shfl_xor(v, 4);
            v += __shfl_xor(v, 8);   // sum over this wave's 16 cols (l15 group)
            if (l15 == 0) atomicAdd(&rs[mi * 16 + l4 * 4 + j], v);
        }
    }
    __syncthreads();

    #pragma unroll
    for (int mi = 0; mi < 4; ++mi) {
        #pragma unroll
        for (int j = 0; j < 4; ++j) {
            const int rl = mi * 16 + l4 * 4 + j;
            const float rinv = __builtin_amdgcn_rcpf(rs[rl]);
            float4 o;
            o.x = acc[mi][0][j] * rinv;
            o.y = acc[mi][1][j] * rinv;
            o.z = acc[mi][2][j] * rinv;
            o.w = acc[mi][3][j] * rinv;
            *reinterpret_cast<float4*>(out + (size_t)(nb + rl) * K_CENT
                                       + w * 64 + l15 * 4) = o;
        }
    }
}

extern "C" void kernel_launch(void* const* d_in, const int* in_sizes, int n_in,
                              void* d_out, int out_size, void* d_ws, size_t ws_size,
                              hipStream_t stream) {
    const float* feats = (const float*)d_in[0];   // [32768, 512] fp32
    const float* cents = (const float*)d_in[1];   // [1024, 512] fp32
    float* out = (float*)d_out;                   // [32768, 1024] fp32

    prep_centers<<<K_CENT, 64, 0, stream>>>(cents);
    fuzzy_mu_kernel<<<N_ROWS / 64, 1024, 0, stream>>>(feats, out);
}